// Round 10
// baseline (214.991 us; speedup 1.0000x reference)
//
#include <hip/hip_runtime.h>
#include <hip/hip_bf16.h>

// ---------------------------------------------------------------------------
// NHRepNet fused forward, Round 10: 48-pt tiles at the 64-reg tier.
//
// Established facts (R1-R9 counters):
//  - Reg-file occupancy tiers are power-of-2 ONLY: <=64 regs -> 8 waves/SIMD,
//    <=128 -> 4, <=256 -> 2 (R3/R9 both measured 4 waves despite asking more).
//  - At-cap register budgets spill to scratch (R5/R6: 145-160MB HBM writes).
//  - Per-point A(weight)-traffic = 128KB / points-per-tile; B(act)-LDS
//    traffic = 512B * (256/C) per pt per layer; VALU epilogue ~57us floor
//    (179M softplus evals, 2 quarter-rate trans each).
//  - R9 (4 waves/SIMD): pipes VALU 57 / L2-A 41 / LDS 36 / MFMA 36us but wall
//    128us -> ~70us phase-serialization loss. Occupancy is the lever.
//
// R10: C=32, nt=3 -> acc[2][3]=24 AGPR + ~36 VGPR = ~60 <= 64 ==> 8 waves/
// SIMD, 4 blocks/CU (LDS 26.1KB x 4 = 104KB), 32 waves/CU. A-traffic
// 2.67KB/pt. Grid 2084 = 2.03 rounds. Everything else is R4/R9's proven
// structure: in-place act (LDA=264), 2 barriers/layer, t2-domain folding.
// ---------------------------------------------------------------------------

using bf16x8 = __attribute__((ext_vector_type(8))) __bf16;
using f32x4  = __attribute__((ext_vector_type(4))) float;

#define LDA 264   // padded activation row stride (bf16)

#define OFFW0 0
#define OFFW1 8192
#define OFFW2 73728
#define OFFW3 139264
#define OFFW4 204800
#define OFFW5 270336
#define OFFW6 335872
#define OFFW7 401408
#define WSB_BYTE_OFF 811008   // fp32 bias region
#define OFFB7 1792            // L0..L6 at l*256; L7 at 1792 (16 floats, padded)

#define SCALE_T2 144.26950408889634f      // 100*log2(e)
#define INV_SQRT2 0.70710678118654752f
#define LN2_100 0.0069314718055994531f    // ln2/100

__device__ __forceinline__ float fast_exp2(float x) {
#if __has_builtin(__builtin_amdgcn_exp2f)
    return __builtin_amdgcn_exp2f(x);
#else
    return exp2f(x);
#endif
}
__device__ __forceinline__ float fast_log2(float x) {
#if __has_builtin(__builtin_amdgcn_logf)
    return __builtin_amdgcn_logf(x);
#else
    return log2f(x);
#endif
}

// a2 = max(t2,0) + log2(1 + 2^-|t2|)   (t2-domain; scales folded into weights)
__device__ __forceinline__ float softplus_t2(float t2) {
    float e = fast_exp2(-fabsf(t2));
    float l = fast_log2(1.0f + e);
    return fmaxf(t2, 0.0f) + l;
}

__device__ __forceinline__ unsigned short bf16_rne(float f) {
    unsigned int u = __float_as_uint(f);
    unsigned int r = u + 0x7FFFu + ((u >> 16) & 1u);
    return (unsigned short)(r >> 16);
}

// One 256-out layer, in-place on act[48][LDA]. 8 waves = 8 channel strips
// (wave owns ch [wave*32, wave*32+32)) covering all 48 points (nt=0..2).
// MODE 1 = layer-3 splice (raw x into ch 253..255; W4 rows absorb scales).
template <int KK, int MODE>
__device__ __forceinline__ void layer_mm(
    const unsigned short* __restrict__ wfrag,
    const float* __restrict__ bias,
    unsigned short* act, const float* xst,
    int wave, int lane)
{
    const int quad = lane >> 4;
    const int l15  = lane & 15;

    f32x4 acc[2][3];
#pragma unroll
    for (int i = 0; i < 2; ++i) {
        const int chb = (wave * 2 + i) * 16 + quad * 4;
        const float4 b4 = *(const float4*)(bias + chb);
#pragma unroll
        for (int nt = 0; nt < 3; ++nt)
            acc[i][nt] = f32x4{b4.x, b4.y, b4.z, b4.w};
    }

    const unsigned short* wbase = wfrag + (wave * 2 * KK * 64 + lane) * 8;

#pragma unroll
    for (int kk = 0; kk < KK; ++kk) {
        bf16x8 bfr[3];
#pragma unroll
        for (int nt = 0; nt < 3; ++nt)
            bfr[nt] = *(const bf16x8*)(act + (nt * 16 + l15) * LDA + kk * 32 + quad * 8);
#pragma unroll
        for (int i = 0; i < 2; ++i) {
            bf16x8 afr = *(const bf16x8*)(wbase + (i * KK + kk) * 512);
#pragma unroll
            for (int nt = 0; nt < 3; ++nt)
                acc[i][nt] = __builtin_amdgcn_mfma_f32_16x16x32_bf16(afr, bfr[nt], acc[i][nt], 0, 0, 0);
        }
    }

    __syncthreads();   // all waves done READING act

#pragma unroll
    for (int i = 0; i < 2; ++i) {
        const int chb = (wave * 2 + i) * 16 + quad * 4;
#pragma unroll
        for (int nt = 0; nt < 3; ++nt) {
            const int pt = nt * 16 + l15;
            float vv[4];
#pragma unroll
            for (int r = 0; r < 4; ++r) {
                float s = softplus_t2(acc[i][nt][r]);
                if (MODE == 1) {
                    const int ch = chb + r;
                    if (ch >= 253)  // splice raw x (W4 rows absorb scales)
                        s = xst[pt * 4 + (ch - 253)];
                }
                vv[r] = s;
            }
            __hip_bfloat162 p01 = __float22bfloat162_rn(float2{vv[0], vv[1]});
            __hip_bfloat162 p23 = __float22bfloat162_rn(float2{vv[2], vv[3]});
            uint2 pk;
            pk.x = *(unsigned int*)&p01;
            pk.y = *(unsigned int*)&p23;
            *(uint2*)(act + pt * LDA + chb) = pk;
        }
    }

    __syncthreads();   // writes visible before next layer reads
}

__global__ __launch_bounds__(512, 8)
void nhrep_main(const float* __restrict__ x, float* __restrict__ out,
                const unsigned short* __restrict__ wsW,
                const float* __restrict__ wsB, int npts)
{
    __shared__ unsigned short act[48 * LDA];   // 25344 B
    __shared__ float xst[48 * 4];              // 768 B -> 26112 B total
    const int tid  = threadIdx.x;
    const int wave = tid >> 6, lane = tid & 63;
    const int quad = lane >> 4, l15 = lane & 15;
    const int base_pt = blockIdx.x * 48;

    // stage x into act channels 0..2, zero-pad to 32 (K-pad for layer 0)
    for (int i = tid; i < 48 * 32; i += 512) {
        const int pt = i >> 5, ch = i & 31;
        const int ptg = base_pt + pt;
        float v = 0.0f;
        if (ch < 3 && ptg < npts) v = x[ptg * 3 + ch];
        act[pt * LDA + ch] = bf16_rne(v);
        if (ch < 4) xst[pt * 4 + ch] = (ch < 3) ? v : 0.0f;
    }
    __syncthreads();

    layer_mm<1, 0>(wsW + OFFW0, wsB + 0 * 256, act, xst, wave, lane);
    layer_mm<8, 0>(wsW + OFFW1, wsB + 1 * 256, act, xst, wave, lane);
    layer_mm<8, 0>(wsW + OFFW2, wsB + 2 * 256, act, xst, wave, lane);
    layer_mm<8, 1>(wsW + OFFW3, wsB + 3 * 256, act, xst, wave, lane);
    layer_mm<8, 0>(wsW + OFFW4, wsB + 4 * 256, act, xst, wave, lane);
    layer_mm<8, 0>(wsW + OFFW5, wsB + 5 * 256, act, xst, wave, lane);
    layer_mm<8, 0>(wsW + OFFW6, wsB + 6 * 256, act, xst, wave, lane);

    // layer 7: 256 -> 8 (W7 pre-scaled ln2/100, b7 raw). Waves 0..2 handle
    // 16 pts each; act not written again -> no barrier.
    if (wave < 3) {
        const float4 b4 = *(const float4*)(wsB + OFFB7 + quad * 4);  // quads>=2: zeros
        f32x4 acc = f32x4{b4.x, b4.y, b4.z, b4.w};
        const unsigned short* w7 = wsW + OFFW7;
#pragma unroll
        for (int kk = 0; kk < 8; ++kk) {
            bf16x8 bfr = *(const bf16x8*)(act + (wave * 16 + l15) * LDA + kk * 32 + quad * 8);
            bf16x8 afr = *(const bf16x8*)(w7 + (kk * 64 + lane) * 8);
            acc = __builtin_amdgcn_mfma_f32_16x16x32_bf16(afr, bfr, acc, 0, 0, 0);
        }
        // quad0 lanes hold ch0-3, quad1 ch4-7 for pt = wave*16+l15
        float u0 = __shfl(acc[0], l15 + 16);
        float u1 = __shfl(acc[1], l15 + 16);
        float u2 = __shfl(acc[2], l15 + 16);
        float u3 = __shfl(acc[3], l15 + 16);
        if (quad == 0) {
            const int ptg = base_pt + wave * 16 + l15;
            if (ptg < npts) {
                const float v0 = acc[0], v1 = acc[1], v2 = acc[2], v3 = acc[3];
                const float v4 = u0, v5 = u1, v6 = u2, v7 = u3;
                const float m23   = fminf(v2, v3);
                const float m67   = fmaxf(v6, v7);
                const float m4567 = fminf(fminf(v4, v5), m67);
                const float h     = fmaxf(fmaxf(v0, v1), fmaxf(m23, m4567));
                float* o = out + (long)ptg * 9;
                o[0] = h;
                o[1] = v0; o[2] = v1; o[3] = v2; o[4] = v3;
                o[5] = v4; o[6] = v5; o[7] = v6; o[8] = v7;
            }
        }
    }
}

// ---------------------------------------------------------------------------
// Fused prepack with scale folding (R4-proven, identity k-mapping).
// Frag (mt,kk,lane,j) = scale(l,k) * W^T[mt*16+(lane&15)][kk*32+(lane>>4)*8+j]
// ---------------------------------------------------------------------------
struct PackArgs {
    const float* W[8];
    const float* b[8];
};

#define TOTAL_FRAGS 50688
#define TOTAL_BIAS  1808

__global__ void prepack_all(PackArgs args, unsigned short* __restrict__ dstW,
                            float* __restrict__ dstB)
{
    const int t = blockIdx.x * blockDim.x + threadIdx.x;
    const int FB[9]  = {0, 1024, 9216, 17408, 25600, 33792, 41984, 50176, 50688};
    const int KKs[8] = {1, 8, 8, 8, 8, 8, 8, 8};
    const int ind[8] = {3, 256, 256, 256, 256, 256, 256, 256};
    const int outd[8]= {256, 256, 256, 253, 256, 256, 256, 8};

    if (t < TOTAL_FRAGS) {
        int l = 0;
        while (t >= FB[l + 1]) ++l;
        const int f    = t - FB[l];
        const int lane = f & 63;
        const int kk   = (f >> 6) % KKs[l];
        const int mt   = f / (64 * KKs[l]);
        const int o    = mt * 16 + (lane & 15);
        const int kb   = kk * 32 + (lane >> 4) * 8;
        const float* W = args.W[l];
        const int in_d = ind[l], out_d = outd[l];

        unsigned short v[8];
#pragma unroll
        for (int j = 0; j < 8; ++j) {
            const int k = kb + j;
            float w = 0.0f;
            if (k < in_d && o < out_d) {
                float sc = 1.0f;
                if (l == 0) sc = SCALE_T2;
                else if (l == 4) sc = (k < 253) ? INV_SQRT2 : (SCALE_T2 * INV_SQRT2);
                else if (l == 7) sc = LN2_100;
                w = W[k * out_d + o] * sc;
            }
            unsigned int u = __float_as_uint(w);
            v[j] = (unsigned short)((u + 0x7FFFu + ((u >> 16) & 1u)) >> 16);
        }
        uint4 p;
        p.x = (unsigned int)v[0] | ((unsigned int)v[1] << 16);
        p.y = (unsigned int)v[2] | ((unsigned int)v[3] << 16);
        p.z = (unsigned int)v[4] | ((unsigned int)v[5] << 16);
        p.w = (unsigned int)v[6] | ((unsigned int)v[7] << 16);
        *(uint4*)(dstW + (long)t * 8) = p;
    } else if (t < TOTAL_FRAGS + TOTAL_BIAS) {
        const int u = t - TOTAL_FRAGS;
        const int l = (u < 1792) ? (u >> 8) : 7;
        const int idx = (l < 7) ? (u & 255) : (u - 1792);
        const float sc = (l < 7) ? SCALE_T2 : 1.0f;   // b7 stays in output units
        dstB[u] = (idx < outd[l]) ? args.b[l][idx] * sc : 0.0f;
    }
}

extern "C" void kernel_launch(void* const* d_in, const int* in_sizes, int n_in,
                              void* d_out, int out_size, void* d_ws, size_t ws_size,
                              hipStream_t stream)
{
    const float* x = (const float*)d_in[0];
    unsigned short* wsW = (unsigned short*)d_ws;
    float* wsB = (float*)((char*)d_ws + WSB_BYTE_OFF);

    PackArgs pa;
    for (int l = 0; l < 8; ++l) {
        pa.W[l] = (const float*)d_in[1 + 2 * l];
        pa.b[l] = (const float*)d_in[2 + 2 * l];
    }
    const int ptot = TOTAL_FRAGS + TOTAL_BIAS;
    prepack_all<<<(ptot + 255) / 256, 256, 0, stream>>>(pa, wsW, wsB);

    const int npts = in_sizes[0] / 3;            // 100000
    const int nblk = (npts + 47) / 48;           // 2084
    nhrep_main<<<nblk, 512, 0, stream>>>(x, (float*)d_out, wsW, wsB, npts);
}

// Round 11
// 193.938 us; speedup vs baseline: 1.1086x; 1.1086x over previous
//
#include <hip/hip_runtime.h>
#include <hip/hip_bf16.h>

// ---------------------------------------------------------------------------
// NHRepNet fused forward, Round 11 = R9 + ping-pong (1 barrier/layer) + tail.
//
// Established facts (R1-R10):
//  - Occupancy tiers are power-of-2: <=64 regs -> 8 w/SIMD, <=128 -> 4, <=256 -> 2.
//  - 64-tier fits at most acc[2][2]+32 arch (R4). acc[2][3] there SPILLS (R10:
//    102MB scratch writes). Spill detector: WRITE_SIZE >> 4MB.
//  - A(weight)-traffic = 128KB/(pts per tile)/layer; only nt cuts it (R8).
//  - R9 (C=32, nt=4, 128-tier, no spill): main 128us; pipes VALU/LDS/L2A/MFMA
//    all 28-40us -> wall dominated by barrier drains + end-of-grid drain.
// R11: (1) ping-pong act -> 8 barriers instead of 15 (safe: layer n+1 writes
// only the buffer layer n read; reads precede each wave's own barrier);
// (2) mixed grid: 1307 x 64-pt blocks + 511 x 32-pt tail blocks (shorter
// drain latency). Same reg structure as R9 (acc[2][4], ~92/128 regs).
// ---------------------------------------------------------------------------

using bf16x8 = __attribute__((ext_vector_type(8))) __bf16;
using f32x4  = __attribute__((ext_vector_type(4))) float;

#define LDA 264   // padded activation row stride (bf16)

#define OFFW0 0
#define OFFW1 8192
#define OFFW2 73728
#define OFFW3 139264
#define OFFW4 204800
#define OFFW5 270336
#define OFFW6 335872
#define OFFW7 401408
#define WSB_BYTE_OFF 811008   // fp32 bias region
#define OFFB7 1792            // L0..L6 at l*256; L7 at 1792 (16 floats, padded)

#define SCALE_T2 144.26950408889634f      // 100*log2(e)
#define INV_SQRT2 0.70710678118654752f
#define LN2_100 0.0069314718055994531f    // ln2/100

__device__ __forceinline__ float fast_exp2(float x) {
#if __has_builtin(__builtin_amdgcn_exp2f)
    return __builtin_amdgcn_exp2f(x);
#else
    return exp2f(x);
#endif
}
__device__ __forceinline__ float fast_log2(float x) {
#if __has_builtin(__builtin_amdgcn_logf)
    return __builtin_amdgcn_logf(x);
#else
    return log2f(x);
#endif
}

// a2 = max(t2,0) + log2(1 + 2^-|t2|)   (t2-domain; scales folded into weights)
__device__ __forceinline__ float softplus_t2(float t2) {
    float e = fast_exp2(-fabsf(t2));
    float l = fast_log2(1.0f + e);
    return fmaxf(t2, 0.0f) + l;
}

__device__ __forceinline__ unsigned short bf16_rne(float f) {
    unsigned int u = __float_as_uint(f);
    unsigned int r = u + 0x7FFFu + ((u >> 16) & 1u);
    return (unsigned short)(r >> 16);
}

// One 256-out layer, src -> dst (ping-pong). 8 waves = 8 channel strips
// (wave owns ch [wave*32, wave*32+32)) for all NT*16 points.
// ONE barrier per layer (at the end). MODE 1 = layer-3 splice.
template <int KK, int MODE, int NT>
__device__ __forceinline__ void layer_mm(
    const unsigned short* __restrict__ wfrag,
    const float* __restrict__ bias,
    const unsigned short* src, unsigned short* dst,
    const float* xst, int wave, int lane)
{
    const int quad = lane >> 4;
    const int l15  = lane & 15;

    f32x4 acc[2][NT];
#pragma unroll
    for (int i = 0; i < 2; ++i) {
        const int chb = (wave * 2 + i) * 16 + quad * 4;
        const float4 b4 = *(const float4*)(bias + chb);
#pragma unroll
        for (int nt = 0; nt < NT; ++nt)
            acc[i][nt] = f32x4{b4.x, b4.y, b4.z, b4.w};
    }

    const unsigned short* wbase = wfrag + (wave * 2 * KK * 64 + lane) * 8;

#pragma unroll
    for (int kk = 0; kk < KK; ++kk) {
        bf16x8 bfr[NT];
#pragma unroll
        for (int nt = 0; nt < NT; ++nt)
            bfr[nt] = *(const bf16x8*)(src + (nt * 16 + l15) * LDA + kk * 32 + quad * 8);
#pragma unroll
        for (int i = 0; i < 2; ++i) {
            bf16x8 afr = *(const bf16x8*)(wbase + (i * KK + kk) * 512);
#pragma unroll
            for (int nt = 0; nt < NT; ++nt)
                acc[i][nt] = __builtin_amdgcn_mfma_f32_16x16x32_bf16(afr, bfr[nt], acc[i][nt], 0, 0, 0);
        }
    }

    // epilogue writes the OTHER buffer: no read/write hazard, no barrier here
#pragma unroll
    for (int i = 0; i < 2; ++i) {
        const int chb = (wave * 2 + i) * 16 + quad * 4;
#pragma unroll
        for (int nt = 0; nt < NT; ++nt) {
            const int pt = nt * 16 + l15;
            float vv[4];
#pragma unroll
            for (int r = 0; r < 4; ++r) {
                float s = softplus_t2(acc[i][nt][r]);
                if (MODE == 1) {
                    const int ch = chb + r;
                    if (ch >= 253)  // splice raw x (W4 rows absorb scales)
                        s = xst[pt * 4 + (ch - 253)];
                }
                vv[r] = s;
            }
            __hip_bfloat162 p01 = __float22bfloat162_rn(float2{vv[0], vv[1]});
            __hip_bfloat162 p23 = __float22bfloat162_rn(float2{vv[2], vv[3]});
            uint2 pk;
            pk.x = *(unsigned int*)&p01;
            pk.y = *(unsigned int*)&p23;
            *(uint2*)(dst + pt * LDA + chb) = pk;
        }
    }

    __syncthreads();   // dst visible before next layer reads it
}

// Full network for one tile of NT*16 points. actA/actB are ping-pong buffers.
template <int NT>
__device__ __forceinline__ void run_net(
    const float* __restrict__ x, float* __restrict__ out,
    const unsigned short* __restrict__ wsW, const float* __restrict__ wsB,
    unsigned short* actA, unsigned short* actB, float* xst,
    int base_pt, int npts, int tid)
{
    const int wave = tid >> 6, lane = tid & 63;
    const int quad = lane >> 4, l15 = lane & 15;

    // stage x into actA channels 0..2, zero-pad to 32 (K-pad for layer 0)
    for (int i = tid; i < NT * 16 * 32; i += 512) {
        const int pt = i >> 5, ch = i & 31;
        const int ptg = base_pt + pt;
        float v = 0.0f;
        if (ch < 3 && ptg < npts) v = x[ptg * 3 + ch];
        actA[pt * LDA + ch] = bf16_rne(v);
        if (ch < 4) xst[pt * 4 + ch] = (ch < 3) ? v : 0.0f;
    }
    __syncthreads();

    layer_mm<1, 0, NT>(wsW + OFFW0, wsB + 0 * 256, actA, actB, xst, wave, lane);
    layer_mm<8, 0, NT>(wsW + OFFW1, wsB + 1 * 256, actB, actA, xst, wave, lane);
    layer_mm<8, 0, NT>(wsW + OFFW2, wsB + 2 * 256, actA, actB, xst, wave, lane);
    layer_mm<8, 1, NT>(wsW + OFFW3, wsB + 3 * 256, actB, actA, xst, wave, lane);
    layer_mm<8, 0, NT>(wsW + OFFW4, wsB + 4 * 256, actA, actB, xst, wave, lane);
    layer_mm<8, 0, NT>(wsW + OFFW5, wsB + 5 * 256, actB, actA, xst, wave, lane);
    layer_mm<8, 0, NT>(wsW + OFFW6, wsB + 6 * 256, actA, actB, xst, wave, lane);
    // final activations in actB

    // layer 7: 256 -> 8 (W7 pre-scaled ln2/100, b7 raw). Waves 0..NT-1 handle
    // 16 pts each; nothing written after -> no barrier.
    if (wave < NT) {
        const float4 b4 = *(const float4*)(wsB + OFFB7 + quad * 4);  // quads>=2: zeros
        f32x4 acc = f32x4{b4.x, b4.y, b4.z, b4.w};
        const unsigned short* w7 = wsW + OFFW7;
#pragma unroll
        for (int kk = 0; kk < 8; ++kk) {
            bf16x8 bfr = *(const bf16x8*)(actB + (wave * 16 + l15) * LDA + kk * 32 + quad * 8);
            bf16x8 afr = *(const bf16x8*)(w7 + (kk * 64 + lane) * 8);
            acc = __builtin_amdgcn_mfma_f32_16x16x32_bf16(afr, bfr, acc, 0, 0, 0);
        }
        // quad0 lanes hold ch0-3, quad1 ch4-7 for pt = wave*16+l15
        float u0 = __shfl(acc[0], l15 + 16);
        float u1 = __shfl(acc[1], l15 + 16);
        float u2 = __shfl(acc[2], l15 + 16);
        float u3 = __shfl(acc[3], l15 + 16);
        if (quad == 0) {
            const int ptg = base_pt + wave * 16 + l15;
            if (ptg < npts) {
                const float v0 = acc[0], v1 = acc[1], v2 = acc[2], v3 = acc[3];
                const float v4 = u0, v5 = u1, v6 = u2, v7 = u3;
                const float m23   = fminf(v2, v3);
                const float m67   = fmaxf(v6, v7);
                const float m4567 = fminf(fminf(v4, v5), m67);
                const float h     = fmaxf(fmaxf(v0, v1), fmaxf(m23, m4567));
                float* o = out + (long)ptg * 9;
                o[0] = h;
                o[1] = v0; o[2] = v1; o[3] = v2; o[4] = v3;
                o[5] = v4; o[6] = v5; o[7] = v6; o[8] = v7;
            }
        }
    }
}

__global__ __launch_bounds__(512, 4)
void nhrep_main(const float* __restrict__ x, float* __restrict__ out,
                const unsigned short* __restrict__ wsW,
                const float* __restrict__ wsB, int npts, int nbig)
{
    __shared__ unsigned short actA[64 * LDA];  // 33792 B
    __shared__ unsigned short actB[64 * LDA];  // 33792 B
    __shared__ float xst[64 * 4];              // 1024 B -> 68608 B (2 blk/CU)
    const int b = blockIdx.x;
    if (b < nbig) {
        run_net<4>(x, out, wsW, wsB, actA, actB, xst, b * 64, npts, threadIdx.x);
    } else {
        run_net<2>(x, out, wsW, wsB, actA, actB, xst,
                   nbig * 64 + (b - nbig) * 32, npts, threadIdx.x);
    }
}

// ---------------------------------------------------------------------------
// Fused prepack with scale folding (R4-proven, identity k-mapping).
// Frag (mt,kk,lane,j) = scale(l,k) * W^T[mt*16+(lane&15)][kk*32+(lane>>4)*8+j]
// ---------------------------------------------------------------------------
struct PackArgs {
    const float* W[8];
    const float* b[8];
};

#define TOTAL_FRAGS 50688
#define TOTAL_BIAS  1808

__global__ void prepack_all(PackArgs args, unsigned short* __restrict__ dstW,
                            float* __restrict__ dstB)
{
    const int t = blockIdx.x * blockDim.x + threadIdx.x;
    const int FB[9]  = {0, 1024, 9216, 17408, 25600, 33792, 41984, 50176, 50688};
    const int KKs[8] = {1, 8, 8, 8, 8, 8, 8, 8};
    const int ind[8] = {3, 256, 256, 256, 256, 256, 256, 256};
    const int outd[8]= {256, 256, 256, 253, 256, 256, 256, 8};

    if (t < TOTAL_FRAGS) {
        int l = 0;
        while (t >= FB[l + 1]) ++l;
        const int f    = t - FB[l];
        const int lane = f & 63;
        const int kk   = (f >> 6) % KKs[l];
        const int mt   = f / (64 * KKs[l]);
        const int o    = mt * 16 + (lane & 15);
        const int kb   = kk * 32 + (lane >> 4) * 8;
        const float* W = args.W[l];
        const int in_d = ind[l], out_d = outd[l];

        unsigned short v[8];
#pragma unroll
        for (int j = 0; j < 8; ++j) {
            const int k = kb + j;
            float w = 0.0f;
            if (k < in_d && o < out_d) {
                float sc = 1.0f;
                if (l == 0) sc = SCALE_T2;
                else if (l == 4) sc = (k < 253) ? INV_SQRT2 : (SCALE_T2 * INV_SQRT2);
                else if (l == 7) sc = LN2_100;
                w = W[k * out_d + o] * sc;
            }
            unsigned int u = __float_as_uint(w);
            v[j] = (unsigned short)((u + 0x7FFFu + ((u >> 16) & 1u)) >> 16);
        }
        uint4 p;
        p.x = (unsigned int)v[0] | ((unsigned int)v[1] << 16);
        p.y = (unsigned int)v[2] | ((unsigned int)v[3] << 16);
        p.z = (unsigned int)v[4] | ((unsigned int)v[5] << 16);
        p.w = (unsigned int)v[6] | ((unsigned int)v[7] << 16);
        *(uint4*)(dstW + (long)t * 8) = p;
    } else if (t < TOTAL_FRAGS + TOTAL_BIAS) {
        const int u = t - TOTAL_FRAGS;
        const int l = (u < 1792) ? (u >> 8) : 7;
        const int idx = (l < 7) ? (u & 255) : (u - 1792);
        const float sc = (l < 7) ? SCALE_T2 : 1.0f;   // b7 stays in output units
        dstB[u] = (idx < outd[l]) ? args.b[l][idx] * sc : 0.0f;
    }
}

extern "C" void kernel_launch(void* const* d_in, const int* in_sizes, int n_in,
                              void* d_out, int out_size, void* d_ws, size_t ws_size,
                              hipStream_t stream)
{
    const float* x = (const float*)d_in[0];
    unsigned short* wsW = (unsigned short*)d_ws;
    float* wsB = (float*)((char*)d_ws + WSB_BYTE_OFF);

    PackArgs pa;
    for (int l = 0; l < 8; ++l) {
        pa.W[l] = (const float*)d_in[1 + 2 * l];
        pa.b[l] = (const float*)d_in[2 + 2 * l];
    }
    const int ptot = TOTAL_FRAGS + TOTAL_BIAS;
    prepack_all<<<(ptot + 255) / 256, 256, 0, stream>>>(pa, wsW, wsB);

    const int npts = in_sizes[0] / 3;            // 100000
    // Mixed grid: 64-pt blocks for the bulk, ~512 32-pt blocks for the drain
    // tail (shorter per-block latency when the grid is nearly empty).
    int nbig, nsmall;
    const int tail_pts = 16384;                  // ~512 small blocks
    if (npts > tail_pts) {
        nbig = (npts - tail_pts + 63) / 64;      // 1307
        const int base_small = nbig * 64;
        nsmall = (npts - base_small + 31) / 32;  // ~511
    } else {
        nbig = 0;
        nsmall = (npts + 31) / 32;
    }
    nhrep_main<<<nbig + nsmall, 512, 0, stream>>>(x, (float*)d_out, wsW, wsB,
                                                  npts, nbig);
}